// Round 4
// baseline (1059.916 us; speedup 1.0000x reference)
//
#include <hip/hip_runtime.h>
#include <hip/hip_bf16.h>

#define NN 100000
#define NE 3200000
#define IN_F 512
#define NH 64
#define NC 16
#define K_HOPS 10

typedef short bf16x8 __attribute__((ext_vector_type(8)));
typedef float f32x4 __attribute__((ext_vector_type(4)));

__device__ __forceinline__ short f2bf_s(float x) {
    __hip_bfloat16 b = __float2bfloat16(x);
    return *reinterpret_cast<short*>(&b);
}
__device__ __forceinline__ float bf2f_s(short s) {
    __hip_bfloat16 b = *reinterpret_cast<__hip_bfloat16*>(&s);
    return __bfloat162float(b);
}

// split 8 f32 (two f32x4) into hi/lo bf16x8 fragments
__device__ __forceinline__ void split8(const f32x4 a, const f32x4 b,
                                       bf16x8& hi, bf16x8& lo) {
    float x[8] = {a[0], a[1], a[2], a[3], b[0], b[1], b[2], b[3]};
#pragma unroll
    for (int j = 0; j < 8; ++j) {
        short h = f2bf_s(x[j]);
        hi[j] = h;
        lo[j] = f2bf_s(x[j] - bf2f_s(h));
    }
}

__device__ __forceinline__ f32x4 mfma3(bf16x8 ah, bf16x8 al, bf16x8 bh,
                                       bf16x8 bl, f32x4 c) {
    c = __builtin_amdgcn_mfma_f32_16x16x32_bf16(ah, bh, c, 0, 0, 0);
    c = __builtin_amdgcn_mfma_f32_16x16x32_bf16(ah, bl, c, 0, 0, 0);
    c = __builtin_amdgcn_mfma_f32_16x16x32_bf16(al, bh, c, 0, 0, 0);
    return c;
}

// ---------- prep: W1 -> W1T hi/lo bf16 [64][512], W2 -> W2T hi/lo [16][64] ----------
__global__ __launch_bounds__(256) void conv_w_kernel(
    const float* __restrict__ W1, const float* __restrict__ W2,
    short* __restrict__ w1h, short* __restrict__ w1l,
    short* __restrict__ w2h, short* __restrict__ w2l)
{
    int i = blockIdx.x * 256 + threadIdx.x;
    if (i < IN_F * NH) {
        int k = i >> 6, n = i & 63;          // W1[k][n]
        float v = W1[i];
        short h = f2bf_s(v);
        w1h[n * IN_F + k] = h;
        w1l[n * IN_F + k] = f2bf_s(v - bf2f_s(h));
    } else if (i < IN_F * NH + NH * NC) {
        int j = i - IN_F * NH;
        int k = j >> 4, c = j & 15;          // W2[k][c]
        float v = W2[j];
        short h = f2bf_s(v);
        w2h[c * NH + k] = h;
        w2l[c * NH + k] = f2bf_s(v - bf2f_s(h));
    }
}

// ---------- encoder: z = relu(X@W1+b1)@W2+b2 ; hid = temp[0]*z ----------
__global__ __launch_bounds__(256) void encoder_mfma(
    const float* __restrict__ X,
    const short* __restrict__ w1h, const short* __restrict__ w1l,
    const short* __restrict__ w2h, const short* __restrict__ w2l,
    const float* __restrict__ b1, const float* __restrict__ b2,
    const float* __restrict__ temp,
    float* __restrict__ z, float* __restrict__ hid)
{
    __shared__ float hs[128 * 68];           // [128 rows][68 pad] f32
    const int t = threadIdx.x;
    const int wave = t >> 6, lane = t & 63;
    const int lm = lane & 15, kg = lane >> 4;
    const int wrow = blockIdx.x * 128 + wave * 32;

    int r0 = wrow + lm;       if (r0 > NN - 1) r0 = NN - 1;
    int r1 = wrow + 16 + lm;  if (r1 > NN - 1) r1 = NN - 1;
    const float* xp0 = X + (size_t)r0 * IN_F + kg * 8;
    const float* xp1 = X + (size_t)r1 * IN_F + kg * 8;
    const short* bhp = w1h + lm * IN_F + kg * 8;
    const short* blp = w1l + lm * IN_F + kg * 8;

    f32x4 acc[2][4];
#pragma unroll
    for (int m = 0; m < 2; ++m)
#pragma unroll
        for (int n = 0; n < 4; ++n) acc[m][n] = (f32x4){0.f, 0.f, 0.f, 0.f};

    for (int kb = 0; kb < IN_F; kb += 32) {
        bf16x8 ah0, al0, ah1, al1;
        {
            const f32x4* p0 = reinterpret_cast<const f32x4*>(xp0 + kb);
            split8(p0[0], p0[1], ah0, al0);
            const f32x4* p1 = reinterpret_cast<const f32x4*>(xp1 + kb);
            split8(p1[0], p1[1], ah1, al1);
        }
#pragma unroll
        for (int nt = 0; nt < 4; ++nt) {
            bf16x8 bh = *reinterpret_cast<const bf16x8*>(bhp + nt * 16 * IN_F + kb);
            bf16x8 bl = *reinterpret_cast<const bf16x8*>(blp + nt * 16 * IN_F + kb);
            acc[0][nt] = mfma3(ah0, al0, bh, bl, acc[0][nt]);
            acc[1][nt] = mfma3(ah1, al1, bh, bl, acc[1][nt]);
        }
    }

    float b1v[4];
#pragma unroll
    for (int nt = 0; nt < 4; ++nt) b1v[nt] = b1[nt * 16 + lm];
#pragma unroll
    for (int m = 0; m < 2; ++m)
#pragma unroll
        for (int nt = 0; nt < 4; ++nt)
#pragma unroll
            for (int r = 0; r < 4; ++r) {
                float v = acc[m][nt][r] + b1v[nt];
                v = v > 0.f ? v : 0.f;
                hs[(wave * 32 + m * 16 + kg * 4 + r) * 68 + nt * 16 + lm] = v;
            }

    f32x4 acc2[2];
    acc2[0] = (f32x4){0.f, 0.f, 0.f, 0.f};
    acc2[1] = (f32x4){0.f, 0.f, 0.f, 0.f};
#pragma unroll
    for (int kb = 0; kb < NH; kb += 32) {
        bf16x8 bh = *reinterpret_cast<const bf16x8*>(w2h + lm * NH + kb + kg * 8);
        bf16x8 bl = *reinterpret_cast<const bf16x8*>(w2l + lm * NH + kb + kg * 8);
#pragma unroll
        for (int m = 0; m < 2; ++m) {
            const f32x4* hp = reinterpret_cast<const f32x4*>(
                &hs[(wave * 32 + m * 16 + lm) * 68 + kb + kg * 8]);
            bf16x8 ah, al;
            split8(hp[0], hp[1], ah, al);
            acc2[m] = mfma3(ah, al, bh, bl, acc2[m]);
        }
    }

    const float b2v = b2[lm];
    const float t0 = temp[0];
#pragma unroll
    for (int m = 0; m < 2; ++m)
#pragma unroll
        for (int r = 0; r < 4; ++r) {
            int node = wrow + m * 16 + kg * 4 + r;
            if (node < NN) {
                float zv = acc2[m][r] + b2v;
                z[(size_t)node * NC + lm] = zv;
                hid[(size_t)node * NC + lm] = t0 * zv;
            }
        }
}

// ---------- CSR build ----------
__global__ __launch_bounds__(256) void hist_kernel(const int* __restrict__ dst,
                                                   int* __restrict__ cnt)
{
    int e = blockIdx.x * 256 + threadIdx.x;
    if (e < NE) atomicAdd(&cnt[dst[e]], 1);
}

__global__ __launch_bounds__(256) void scan1_kernel(const int* __restrict__ cnt,
                                                    int* __restrict__ excl,
                                                    int* __restrict__ bsum)
{
    __shared__ int s[256];
    int tid = threadIdx.x;
    int d = blockIdx.x * 256 + tid;
    int v = (d < NN) ? cnt[d] : 0;
    s[tid] = v;
    __syncthreads();
    for (int off = 1; off < 256; off <<= 1) {
        int u = (tid >= off) ? s[tid - off] : 0;
        __syncthreads();
        s[tid] += u;
        __syncthreads();
    }
    if (d < NN) excl[d] = s[tid] - v;
    if (tid == 255) bsum[blockIdx.x] = s[255];
}

#define NBLK 391
__global__ __launch_bounds__(512) void scan2_kernel(const int* __restrict__ bsum,
                                                    int* __restrict__ boff)
{
    __shared__ int s[512];
    int tid = threadIdx.x;
    int v = (tid < NBLK) ? bsum[tid] : 0;
    s[tid] = v;
    __syncthreads();
    for (int off = 1; off < 512; off <<= 1) {
        int u = (tid >= off) ? s[tid - off] : 0;
        __syncthreads();
        s[tid] += u;
        __syncthreads();
    }
    if (tid < NBLK) boff[tid] = s[tid] - v;
}

__global__ __launch_bounds__(256) void scan3_kernel(const int* __restrict__ excl,
                                                    const int* __restrict__ boff,
                                                    int* __restrict__ row_start,
                                                    int* __restrict__ cursor)
{
    int d = blockIdx.x * 256 + threadIdx.x;
    if (d < NN) {
        int rs = excl[d] + boff[blockIdx.x];
        row_start[d] = rs;
        cursor[d] = rs;
    }
}

// fill packed (src, w) per CSR slot: one scattered 8B store per edge
__global__ __launch_bounds__(256) void fill_kernel(
    const int* __restrict__ src, const int* __restrict__ dst,
    const float* __restrict__ w, int* __restrict__ cursor,
    int2* __restrict__ ew)
{
    int e = blockIdx.x * 256 + threadIdx.x;
    if (e < NE) {
        int d = dst[e];
        int p = atomicAdd(&cursor[d], 1);
        ew[p] = make_int2(src[e], __float_as_int(w[e]));
    }
}

// ---------- hop: out[d] = sum_e w*in[src]; hid[d] += temp[k]*out[d] ----------
// 4 lanes per dst row, float4 per lane (one 64B line per edge).
__global__ __launch_bounds__(256) void hop_kernel(
    const int* __restrict__ row_start, const int2* __restrict__ ew,
    const float* __restrict__ in, float* __restrict__ out,
    float* __restrict__ hid, const float* __restrict__ temp, int k, int last)
{
    int tid = blockIdx.x * 256 + threadIdx.x;
    int d = tid >> 2, cg = tid & 3;
    if (d >= NN) return;
    int e = row_start[d];
    const int e1 = (d + 1 < NN) ? row_start[d + 1] : NE;
    const f32x4* inv = reinterpret_cast<const f32x4*>(in);   // [NN][4] x f32x4
    f32x4 a0 = (f32x4){0.f, 0.f, 0.f, 0.f};
    f32x4 a1 = (f32x4){0.f, 0.f, 0.f, 0.f};
    for (; e + 1 < e1; e += 2) {
        int2 p0 = ew[e];
        int2 p1 = ew[e + 1];
        f32x4 v0 = inv[(size_t)p0.x * 4 + cg];
        f32x4 v1 = inv[(size_t)p1.x * 4 + cg];
        float w0 = __int_as_float(p0.y);
        float w1 = __int_as_float(p1.y);
        a0 += w0 * v0;
        a1 += w1 * v1;
    }
    if (e < e1) {
        int2 p0 = ew[e];
        f32x4 v0 = inv[(size_t)p0.x * 4 + cg];
        a0 += __int_as_float(p0.y) * v0;
    }
    f32x4 r = a0 + a1;
    size_t o = (size_t)d * 4 + cg;
    if (!last) reinterpret_cast<f32x4*>(out)[o] = r;
    const float tk = temp[k];
    f32x4 h = reinterpret_cast<f32x4*>(hid)[o];
    h += tk * r;
    reinterpret_cast<f32x4*>(hid)[o] = h;
}

// ---------- fallback (small ws): atomic scatter + axpy ----------
__global__ __launch_bounds__(256) void spmm_atomic_kernel(
    const int* __restrict__ src, const int* __restrict__ dst,
    const float* __restrict__ w, const float* __restrict__ in,
    float* __restrict__ out)
{
    int tid = blockIdx.x * 256 + threadIdx.x;
    int e = tid >> 4, c = tid & 15;
    if (e >= NE) return;
    float val = w[e] * in[(size_t)src[e] * NC + c];
    atomicAdd(&out[(size_t)dst[e] * NC + c], val);
}
__global__ __launch_bounds__(256) void axpy_kernel(
    float* __restrict__ hid, const float* __restrict__ zk,
    const float* __restrict__ temp, int k)
{
    int i = blockIdx.x * 256 + threadIdx.x;
    if (i < NN * NC) hid[i] += temp[k] * zk[i];
}

extern "C" void kernel_launch(void* const* d_in, const int* in_sizes, int n_in,
                              void* d_out, int out_size, void* d_ws, size_t ws_size,
                              hipStream_t stream)
{
    const float* feature = (const float*)d_in[0];
    const float* W1      = (const float*)d_in[1];
    const float* b1      = (const float*)d_in[2];
    const float* W2      = (const float*)d_in[3];
    const float* b2      = (const float*)d_in[4];
    const int*   edges   = (const int*)d_in[5];
    const float* norm_A  = (const float*)d_in[6];
    const float* temp    = (const float*)d_in[7];
    const int* src = edges;
    const int* dst = edges + NE;
    float* hid = (float*)d_out;

    char* p = (char*)d_ws;
    size_t off = 0;
    auto carve = [&](size_t bytes) {
        void* r = p + off;
        off += (bytes + 255) & ~(size_t)255;
        return r;
    };
    float* zkA  = (float*)carve((size_t)NN * NC * 4);
    float* zkB  = (float*)carve((size_t)NN * NC * 4);
    short* w1h  = (short*)carve((size_t)IN_F * NH * 2);
    short* w1l  = (short*)carve((size_t)IN_F * NH * 2);
    short* w2h  = (short*)carve((size_t)NH * NC * 2);
    short* w2l  = (short*)carve((size_t)NH * NC * 2);
    int*   cnt      = (int*)carve((size_t)NN * 4);
    int*   excl     = (int*)carve((size_t)NN * 4);
    int*   rowst    = (int*)carve((size_t)NN * 4);
    int*   cursor   = (int*)carve((size_t)NN * 4);
    int*   bsum     = (int*)carve(2048);
    int*   boff     = (int*)carve(2048);
    int2*  ew       = (int2*)carve((size_t)NE * 8);
    const bool useCSR = (off <= ws_size);

    conv_w_kernel<<<(IN_F * NH + NH * NC + 255) / 256, 256, 0, stream>>>(
        W1, W2, w1h, w1l, w2h, w2l);
    encoder_mfma<<<(NN + 127) / 128, 256, 0, stream>>>(
        feature, w1h, w1l, w2h, w2l, b1, b2, temp, zkA, hid);

    const int edgeGrid = (NE + 255) / 256;           // 12500

    if (useCSR) {
        hipMemsetAsync(cnt, 0, (size_t)NN * 4, stream);
        hist_kernel<<<edgeGrid, 256, 0, stream>>>(dst, cnt);
        scan1_kernel<<<NBLK, 256, 0, stream>>>(cnt, excl, bsum);
        scan2_kernel<<<1, 512, 0, stream>>>(bsum, boff);
        scan3_kernel<<<NBLK, 256, 0, stream>>>(excl, boff, rowst, cursor);
        fill_kernel<<<edgeGrid, 256, 0, stream>>>(src, dst, norm_A, cursor, ew);

        const int hopGrid = (NN * 4 + 255) / 256;    // 1563
        float* cur = zkA;
        float* nxt = zkB;
        for (int k = 1; k <= K_HOPS; ++k) {
            hop_kernel<<<hopGrid, 256, 0, stream>>>(rowst, ew, cur, nxt, hid,
                                                    temp, k, k == K_HOPS);
            float* t2 = cur; cur = nxt; nxt = t2;
        }
    } else {
        const int spmmGrid = (NE * NC + 255) / 256;
        const int vecGrid  = (NN * NC + 255) / 256;
        float* cur = zkA;
        float* nxt = zkB;
        for (int k = 1; k <= K_HOPS; ++k) {
            hipMemsetAsync(nxt, 0, (size_t)NN * NC * 4, stream);
            spmm_atomic_kernel<<<spmmGrid, 256, 0, stream>>>(src, dst, norm_A, cur, nxt);
            axpy_kernel<<<vecGrid, 256, 0, stream>>>(hid, nxt, temp, k);
            float* t2 = cur; cur = nxt; nxt = t2;
        }
    }
}

// Round 5
// 759.683 us; speedup vs baseline: 1.3952x; 1.3952x over previous
//
#include <hip/hip_runtime.h>
#include <hip/hip_bf16.h>

#define NN 100000
#define NE 3200000
#define IN_F 512
#define NH 64
#define NC 16
#define K_HOPS 10

#define BSPAN 64                      // dst-nodes per bucket
#define NBUCK 2048                    // power-of-2 >= NN/BSPAN
#define NBUCK_USED ((NN + BSPAN - 1) / BSPAN)   // 1563
#define PART_BLOCKS 200
#define CHUNK (NE / PART_BLOCKS)      // 16000
#define MAXBE 4096                    // LDS staging cap per bucket (avg 2048)

typedef short bf16x8 __attribute__((ext_vector_type(8)));
typedef float f32x4 __attribute__((ext_vector_type(4)));
typedef unsigned short u16;
typedef u16 u16x4 __attribute__((ext_vector_type(4)));

__device__ __forceinline__ short f2bf_s(float x) {
    __hip_bfloat16 b = __float2bfloat16(x);
    return *reinterpret_cast<short*>(&b);
}
__device__ __forceinline__ float bf2f_s(short s) {
    __hip_bfloat16 b = *reinterpret_cast<__hip_bfloat16*>(&s);
    return __bfloat162float(b);
}
__device__ __forceinline__ f32x4 bf4_to_f32(u16x4 v) {
    f32x4 r;
    r[0] = __uint_as_float((unsigned)v[0] << 16);
    r[1] = __uint_as_float((unsigned)v[1] << 16);
    r[2] = __uint_as_float((unsigned)v[2] << 16);
    r[3] = __uint_as_float((unsigned)v[3] << 16);
    return r;
}

__device__ __forceinline__ void split8(const f32x4 a, const f32x4 b,
                                       bf16x8& hi, bf16x8& lo) {
    float x[8] = {a[0], a[1], a[2], a[3], b[0], b[1], b[2], b[3]};
#pragma unroll
    for (int j = 0; j < 8; ++j) {
        short h = f2bf_s(x[j]);
        hi[j] = h;
        lo[j] = f2bf_s(x[j] - bf2f_s(h));
    }
}

__device__ __forceinline__ f32x4 mfma3(bf16x8 ah, bf16x8 al, bf16x8 bh,
                                       bf16x8 bl, f32x4 c) {
    c = __builtin_amdgcn_mfma_f32_16x16x32_bf16(ah, bh, c, 0, 0, 0);
    c = __builtin_amdgcn_mfma_f32_16x16x32_bf16(ah, bl, c, 0, 0, 0);
    c = __builtin_amdgcn_mfma_f32_16x16x32_bf16(al, bh, c, 0, 0, 0);
    return c;
}

// ---------- prep: W1 -> W1T hi/lo bf16, W2 -> W2T hi/lo ----------
__global__ __launch_bounds__(256) void conv_w_kernel(
    const float* __restrict__ W1, const float* __restrict__ W2,
    short* __restrict__ w1h, short* __restrict__ w1l,
    short* __restrict__ w2h, short* __restrict__ w2l)
{
    int i = blockIdx.x * 256 + threadIdx.x;
    if (i < IN_F * NH) {
        int k = i >> 6, n = i & 63;
        float v = W1[i];
        short h = f2bf_s(v);
        w1h[n * IN_F + k] = h;
        w1l[n * IN_F + k] = f2bf_s(v - bf2f_s(h));
    } else if (i < IN_F * NH + NH * NC) {
        int j = i - IN_F * NH;
        int k = j >> 4, c = j & 15;
        float v = W2[j];
        short h = f2bf_s(v);
        w2h[c * NH + k] = h;
        w2l[c * NH + k] = f2bf_s(v - bf2f_s(h));
    }
}

// ---------- encoder: z(bf16) = relu(X@W1+b1)@W2+b2 ; hid = temp[0]*z ----------
__global__ __launch_bounds__(256) void encoder_mfma(
    const float* __restrict__ X,
    const short* __restrict__ w1h, const short* __restrict__ w1l,
    const short* __restrict__ w2h, const short* __restrict__ w2l,
    const float* __restrict__ b1, const float* __restrict__ b2,
    const float* __restrict__ temp,
    u16* __restrict__ z, float* __restrict__ hid)
{
    __shared__ float hs[128 * 68];
    const int t = threadIdx.x;
    const int wave = t >> 6, lane = t & 63;
    const int lm = lane & 15, kg = lane >> 4;
    const int wrow = blockIdx.x * 128 + wave * 32;

    int r0 = wrow + lm;       if (r0 > NN - 1) r0 = NN - 1;
    int r1 = wrow + 16 + lm;  if (r1 > NN - 1) r1 = NN - 1;
    const float* xp0 = X + (size_t)r0 * IN_F + kg * 8;
    const float* xp1 = X + (size_t)r1 * IN_F + kg * 8;
    const short* bhp = w1h + lm * IN_F + kg * 8;
    const short* blp = w1l + lm * IN_F + kg * 8;

    f32x4 acc[2][4];
#pragma unroll
    for (int m = 0; m < 2; ++m)
#pragma unroll
        for (int n = 0; n < 4; ++n) acc[m][n] = (f32x4){0.f, 0.f, 0.f, 0.f};

    for (int kb = 0; kb < IN_F; kb += 32) {
        bf16x8 ah0, al0, ah1, al1;
        {
            const f32x4* p0 = reinterpret_cast<const f32x4*>(xp0 + kb);
            split8(p0[0], p0[1], ah0, al0);
            const f32x4* p1 = reinterpret_cast<const f32x4*>(xp1 + kb);
            split8(p1[0], p1[1], ah1, al1);
        }
#pragma unroll
        for (int nt = 0; nt < 4; ++nt) {
            bf16x8 bh = *reinterpret_cast<const bf16x8*>(bhp + nt * 16 * IN_F + kb);
            bf16x8 bl = *reinterpret_cast<const bf16x8*>(blp + nt * 16 * IN_F + kb);
            acc[0][nt] = mfma3(ah0, al0, bh, bl, acc[0][nt]);
            acc[1][nt] = mfma3(ah1, al1, bh, bl, acc[1][nt]);
        }
    }

    float b1v[4];
#pragma unroll
    for (int nt = 0; nt < 4; ++nt) b1v[nt] = b1[nt * 16 + lm];
#pragma unroll
    for (int m = 0; m < 2; ++m)
#pragma unroll
        for (int nt = 0; nt < 4; ++nt)
#pragma unroll
            for (int r = 0; r < 4; ++r) {
                float v = acc[m][nt][r] + b1v[nt];
                v = v > 0.f ? v : 0.f;
                hs[(wave * 32 + m * 16 + kg * 4 + r) * 68 + nt * 16 + lm] = v;
            }

    f32x4 acc2[2];
    acc2[0] = (f32x4){0.f, 0.f, 0.f, 0.f};
    acc2[1] = (f32x4){0.f, 0.f, 0.f, 0.f};
#pragma unroll
    for (int kb = 0; kb < NH; kb += 32) {
        bf16x8 bh = *reinterpret_cast<const bf16x8*>(w2h + lm * NH + kb + kg * 8);
        bf16x8 bl = *reinterpret_cast<const bf16x8*>(w2l + lm * NH + kb + kg * 8);
#pragma unroll
        for (int m = 0; m < 2; ++m) {
            const f32x4* hp = reinterpret_cast<const f32x4*>(
                &hs[(wave * 32 + m * 16 + lm) * 68 + kb + kg * 8]);
            bf16x8 ah, al;
            split8(hp[0], hp[1], ah, al);
            acc2[m] = mfma3(ah, al, bh, bl, acc2[m]);
        }
    }

    const float b2v = b2[lm];
    const float t0 = temp[0];
#pragma unroll
    for (int m = 0; m < 2; ++m)
#pragma unroll
        for (int r = 0; r < 4; ++r) {
            int node = wrow + m * 16 + kg * 4 + r;
            if (node < NN) {
                float zv = acc2[m][r] + b2v;
                z[(size_t)node * NC + lm] = (u16)f2bf_s(zv);
                hid[(size_t)node * NC + lm] = t0 * zv;
            }
        }
}

// ---------- bucketed CSR build ----------
// global bucket histogram
__global__ __launch_bounds__(256) void ghist_kernel(const int* __restrict__ dst,
                                                    int* __restrict__ gcnt)
{
    __shared__ int h[NBUCK];
    int t = threadIdx.x;
    for (int i = t; i < NBUCK; i += 256) h[i] = 0;
    __syncthreads();
    int s = blockIdx.x * CHUNK;
    int e = s + CHUNK; if (e > NE) e = NE;
    for (int i = s + t; i < e; i += 256) atomicAdd(&h[dst[i] >> 6], 1);
    __syncthreads();
    for (int i = t; i < NBUCK; i += 256)
        if (h[i]) atomicAdd(&gcnt[i], h[i]);
}

// exclusive scan of 2048 bucket counts (single block)
__global__ __launch_bounds__(1024) void gscan_kernel(const int* __restrict__ gcnt,
                                                     int* __restrict__ goff,
                                                     int* __restrict__ gcursor)
{
    __shared__ int a[NBUCK], b[NBUCK];
    int t = threadIdx.x;
    a[t] = gcnt[t]; a[t + 1024] = gcnt[t + 1024];
    __syncthreads();
    int* cur = a; int* nxt = b;
    for (int off = 1; off < NBUCK; off <<= 1) {
        for (int i = t; i < NBUCK; i += 1024) {
            int v = cur[i];
            if (i >= off) v += cur[i - off];
            nxt[i] = v;
        }
        __syncthreads();
        int* tmp = cur; cur = nxt; nxt = tmp;
    }
    for (int i = t; i < NBUCK; i += 1024) {
        int ex = (i == 0) ? 0 : cur[i - 1];
        goff[i] = ex;
        gcursor[i] = ex;
    }
    if (t == 0) goff[NBUCK] = cur[NBUCK - 1];
}

// partition edges into buckets; pack (src | dlo<<26, w) as int2
__global__ __launch_bounds__(256) void partition_kernel(
    const int* __restrict__ src, const int* __restrict__ dst,
    const float* __restrict__ w, int* __restrict__ gcursor,
    int2* __restrict__ ew)
{
    __shared__ int h[NBUCK];
    __shared__ int base[NBUCK];
    __shared__ int rnk[NBUCK];
    int t = threadIdx.x;
    for (int i = t; i < NBUCK; i += 256) h[i] = 0;
    __syncthreads();
    int s = blockIdx.x * CHUNK;
    int e = s + CHUNK; if (e > NE) e = NE;
    for (int i = s + t; i < e; i += 256) atomicAdd(&h[dst[i] >> 6], 1);
    __syncthreads();
    for (int i = t; i < NBUCK; i += 256) {
        int c = h[i];
        base[i] = c ? atomicAdd(&gcursor[i], c) : 0;
        rnk[i] = 0;
    }
    __syncthreads();
    for (int i = s + t; i < e; i += 256) {
        int d = dst[i];
        int b = d >> 6;
        int r = atomicAdd(&rnk[b], 1);
        int pos = base[b] + r;
        unsigned x = (unsigned)src[i] | ((unsigned)(d & 63) << 26);
        ew[pos] = make_int2((int)x, __float_as_int(w[i]));
    }
}

// per-bucket exact CSR: stage in LDS, write back node-sorted, emit rowst
__global__ __launch_bounds__(256) void bucketfill_kernel(
    const int* __restrict__ goff, int2* __restrict__ ew,
    int* __restrict__ rowst)
{
    __shared__ int2 buf[MAXBE];
    __shared__ int cnt[BSPAN], excl[BSPAN], rnk[BSPAN];
    int b = blockIdx.x;
    int s = goff[b];
    int n = goff[b + 1] - s;
    if (n > MAXBE) n = MAXBE;   // impossible for uniform edges; guards LDS
    int t = threadIdx.x;
    if (t < BSPAN) cnt[t] = 0;
    __syncthreads();
    for (int i = t; i < n; i += 256) {
        int2 v = ew[s + i];
        buf[i] = v;
        atomicAdd(&cnt[((unsigned)v.x) >> 26], 1);
    }
    __syncthreads();
    if (t == 0) {
        int run = 0;
        for (int i = 0; i < BSPAN; ++i) { excl[i] = run; run += cnt[i]; }
    }
    __syncthreads();
    if (t < BSPAN) {
        int node = b * BSPAN + t;
        if (node < NN) rowst[node] = s + excl[t];
        rnk[t] = 0;
    }
    __syncthreads();
    for (int i = t; i < n; i += 256) {
        int2 v = buf[i];
        unsigned x = (unsigned)v.x;
        int d = x >> 26;
        int r = atomicAdd(&rnk[d], 1);
        ew[s + excl[d] + r] = make_int2((int)(x & 0x03FFFFFFu), v.y);
    }
}

// ---------- hop: r[d] = sum w*in[src] (bf16 in); out=bf16(r); hid += tk*r ----------
__global__ __launch_bounds__(256) void hop_kernel(
    const int* __restrict__ rowst, const long long* __restrict__ ew,
    const u16* __restrict__ in, u16* __restrict__ out,
    float* __restrict__ hid, const float* __restrict__ temp, int k, int last)
{
    int tid = blockIdx.x * 256 + threadIdx.x;
    int d = tid >> 2, cg = tid & 3;
    if (d >= NN) return;
    int e = rowst[d];
    const int e1 = (d + 1 < NN) ? rowst[d + 1] : NE;
    const u16x4* inv = reinterpret_cast<const u16x4*>(in);
    f32x4 a0 = (f32x4){0.f, 0.f, 0.f, 0.f};
    f32x4 a1 = a0, a2 = a0, a3 = a0;
    for (; e + 3 < e1; e += 4) {
        long long q0 = __builtin_nontemporal_load(ew + e);
        long long q1 = __builtin_nontemporal_load(ew + e + 1);
        long long q2 = __builtin_nontemporal_load(ew + e + 2);
        long long q3 = __builtin_nontemporal_load(ew + e + 3);
        int s0 = (int)(unsigned)(q0 & 0xFFFFFFFFll);
        int s1 = (int)(unsigned)(q1 & 0xFFFFFFFFll);
        int s2 = (int)(unsigned)(q2 & 0xFFFFFFFFll);
        int s3 = (int)(unsigned)(q3 & 0xFFFFFFFFll);
        float w0 = __uint_as_float((unsigned)((unsigned long long)q0 >> 32));
        float w1 = __uint_as_float((unsigned)((unsigned long long)q1 >> 32));
        float w2 = __uint_as_float((unsigned)((unsigned long long)q2 >> 32));
        float w3 = __uint_as_float((unsigned)((unsigned long long)q3 >> 32));
        u16x4 v0 = inv[(size_t)s0 * 4 + cg];
        u16x4 v1 = inv[(size_t)s1 * 4 + cg];
        u16x4 v2 = inv[(size_t)s2 * 4 + cg];
        u16x4 v3 = inv[(size_t)s3 * 4 + cg];
        a0 += w0 * bf4_to_f32(v0);
        a1 += w1 * bf4_to_f32(v1);
        a2 += w2 * bf4_to_f32(v2);
        a3 += w3 * bf4_to_f32(v3);
    }
    for (; e < e1; ++e) {
        long long q0 = __builtin_nontemporal_load(ew + e);
        int s0 = (int)(unsigned)(q0 & 0xFFFFFFFFll);
        float w0 = __uint_as_float((unsigned)((unsigned long long)q0 >> 32));
        a0 += w0 * bf4_to_f32(inv[(size_t)s0 * 4 + cg]);
    }
    f32x4 r = (a0 + a1) + (a2 + a3);
    size_t o = (size_t)d * 4 + cg;
    if (!last) {
        u16x4 ro;
        ro[0] = (u16)f2bf_s(r[0]);
        ro[1] = (u16)f2bf_s(r[1]);
        ro[2] = (u16)f2bf_s(r[2]);
        ro[3] = (u16)f2bf_s(r[3]);
        reinterpret_cast<u16x4*>(out)[o] = ro;
    }
    const float tk = temp[k];
    reinterpret_cast<f32x4*>(hid)[o] += tk * r;
}

// ---------- fallback (small ws): atomic scatter on bf16 state ----------
__global__ __launch_bounds__(256) void spmm_atomic_bf16(
    const int* __restrict__ src, const int* __restrict__ dst,
    const float* __restrict__ w, const u16* __restrict__ in,
    float* __restrict__ outf)
{
    int tid = blockIdx.x * 256 + threadIdx.x;
    int e = tid >> 4, c = tid & 15;
    if (e >= NE) return;
    float v = __uint_as_float((unsigned)in[(size_t)src[e] * NC + c] << 16);
    atomicAdd(&outf[(size_t)dst[e] * NC + c], w[e] * v);
}
__global__ __launch_bounds__(256) void axpy_quant_kernel(
    float* __restrict__ hid, const float* __restrict__ outf,
    u16* __restrict__ nextb, const float* __restrict__ temp, int k)
{
    int i = blockIdx.x * 256 + threadIdx.x;
    if (i < NN * NC) {
        float r = outf[i];
        hid[i] += temp[k] * r;
        nextb[i] = (u16)f2bf_s(r);
    }
}

extern "C" void kernel_launch(void* const* d_in, const int* in_sizes, int n_in,
                              void* d_out, int out_size, void* d_ws, size_t ws_size,
                              hipStream_t stream)
{
    const float* feature = (const float*)d_in[0];
    const float* W1      = (const float*)d_in[1];
    const float* b1      = (const float*)d_in[2];
    const float* W2      = (const float*)d_in[3];
    const float* b2      = (const float*)d_in[4];
    const int*   edges   = (const int*)d_in[5];
    const float* norm_A  = (const float*)d_in[6];
    const float* temp    = (const float*)d_in[7];
    const int* src = edges;
    const int* dst = edges + NE;
    float* hid = (float*)d_out;

    char* p = (char*)d_ws;
    size_t off = 0;
    auto carve = [&](size_t bytes) {
        void* r = p + off;
        off += (bytes + 255) & ~(size_t)255;
        return r;
    };
    u16*   zkA   = (u16*)carve((size_t)NN * NC * 2);
    u16*   zkB   = (u16*)carve((size_t)NN * NC * 2);
    short* w1h   = (short*)carve((size_t)IN_F * NH * 2);
    short* w1l   = (short*)carve((size_t)IN_F * NH * 2);
    short* w2h   = (short*)carve((size_t)NH * NC * 2);
    short* w2l   = (short*)carve((size_t)NH * NC * 2);
    int*   gcnt  = (int*)carve((size_t)NBUCK * 4);
    int*   goff  = (int*)carve((size_t)(NBUCK + 1) * 4);
    int*   gcur  = (int*)carve((size_t)NBUCK * 4);
    int*   rowst = (int*)carve((size_t)NN * 4);
    int2*  ew    = (int2*)carve((size_t)NE * 8);
    const bool useCSR = (off <= ws_size);

    conv_w_kernel<<<(IN_F * NH + NH * NC + 255) / 256, 256, 0, stream>>>(
        W1, W2, w1h, w1l, w2h, w2l);
    encoder_mfma<<<(NN + 127) / 128, 256, 0, stream>>>(
        feature, w1h, w1l, w2h, w2l, b1, b2, temp, zkA, hid);

    if (useCSR) {
        hipMemsetAsync(gcnt, 0, (size_t)NBUCK * 4, stream);
        ghist_kernel<<<PART_BLOCKS, 256, 0, stream>>>(dst, gcnt);
        gscan_kernel<<<1, 1024, 0, stream>>>(gcnt, goff, gcur);
        partition_kernel<<<PART_BLOCKS, 256, 0, stream>>>(src, dst, norm_A,
                                                          gcur, ew);
        bucketfill_kernel<<<NBUCK_USED, 256, 0, stream>>>(goff, ew, rowst);

        const int hopGrid = (NN * 4 + 255) / 256;    // 1563
        u16* cur = zkA;
        u16* nxt = zkB;
        for (int k = 1; k <= K_HOPS; ++k) {
            hop_kernel<<<hopGrid, 256, 0, stream>>>(
                rowst, (const long long*)ew, cur, nxt, hid, temp, k,
                k == K_HOPS);
            u16* t2 = cur; cur = nxt; nxt = t2;
        }
    } else {
        // minimal fallback: atomic scatter, bf16 state, f32 accum buffer
        char* q = (char*)d_ws;
        u16* inA = (u16*)q;                                   // alias zkA
        u16* inB = (u16*)(q + ((size_t)NN * NC * 2 + 255 & ~(size_t)255));
        float* outf = (float*)(q + 2 * (((size_t)NN * NC * 2 + 255) & ~(size_t)255)
                               + 512 * 1024);                 // past weights
        const int spmmGrid = (NE * NC + 255) / 256;
        const int vecGrid  = (NN * NC + 255) / 256;
        u16* cur = inA; u16* nxt = inB;
        for (int k = 1; k <= K_HOPS; ++k) {
            hipMemsetAsync(outf, 0, (size_t)NN * NC * 4, stream);
            spmm_atomic_bf16<<<spmmGrid, 256, 0, stream>>>(src, dst, norm_A,
                                                           cur, outf);
            axpy_quant_kernel<<<vecGrid, 256, 0, stream>>>(hid, outf, nxt,
                                                           temp, k);
            u16* t2 = cur; cur = nxt; nxt = t2;
        }
    }
}

// Round 6
// 691.500 us; speedup vs baseline: 1.5328x; 1.0986x over previous
//
#include <hip/hip_runtime.h>
#include <hip/hip_bf16.h>

#define NN 100000
#define NE 3200000
#define IN_F 512
#define NH 64
#define NC 16
#define K_HOPS 10

#define BSPAN 256                       // dst-nodes per bucket
#define NBUCKC ((NN + BSPAN - 1) / BSPAN)   // 391
#define NBUCKP 512                      // padded power-of-2
#define CAP 9216                        // region capacity (mean 8192 + 11 sigma)
#define PART_BLOCKS 256
#define PCHUNK ((NE + PART_BLOCKS - 1) / PART_BLOCKS)  // 12500

typedef short bf16x8 __attribute__((ext_vector_type(8)));
typedef float f32x4 __attribute__((ext_vector_type(4)));
typedef unsigned short u16;
typedef u16 u16x4 __attribute__((ext_vector_type(4)));

__device__ __forceinline__ short f2bf_s(float x) {
    __hip_bfloat16 b = __float2bfloat16(x);
    return *reinterpret_cast<short*>(&b);
}
__device__ __forceinline__ float bf2f_s(short s) {
    __hip_bfloat16 b = *reinterpret_cast<__hip_bfloat16*>(&s);
    return __bfloat162float(b);
}
__device__ __forceinline__ f32x4 bf4_to_f32(u16x4 v) {
    f32x4 r;
    r[0] = __uint_as_float((unsigned)v[0] << 16);
    r[1] = __uint_as_float((unsigned)v[1] << 16);
    r[2] = __uint_as_float((unsigned)v[2] << 16);
    r[3] = __uint_as_float((unsigned)v[3] << 16);
    return r;
}

__device__ __forceinline__ void split8(const f32x4 a, const f32x4 b,
                                       bf16x8& hi, bf16x8& lo) {
    float x[8] = {a[0], a[1], a[2], a[3], b[0], b[1], b[2], b[3]};
#pragma unroll
    for (int j = 0; j < 8; ++j) {
        short h = f2bf_s(x[j]);
        hi[j] = h;
        lo[j] = f2bf_s(x[j] - bf2f_s(h));
    }
}

__device__ __forceinline__ f32x4 mfma3(bf16x8 ah, bf16x8 al, bf16x8 bh,
                                       bf16x8 bl, f32x4 c) {
    c = __builtin_amdgcn_mfma_f32_16x16x32_bf16(ah, bh, c, 0, 0, 0);
    c = __builtin_amdgcn_mfma_f32_16x16x32_bf16(ah, bl, c, 0, 0, 0);
    c = __builtin_amdgcn_mfma_f32_16x16x32_bf16(al, bh, c, 0, 0, 0);
    return c;
}

// ---------- prep: W1 -> W1T hi/lo bf16, W2 -> W2T hi/lo ----------
__global__ __launch_bounds__(256) void conv_w_kernel(
    const float* __restrict__ W1, const float* __restrict__ W2,
    short* __restrict__ w1h, short* __restrict__ w1l,
    short* __restrict__ w2h, short* __restrict__ w2l)
{
    int i = blockIdx.x * 256 + threadIdx.x;
    if (i < IN_F * NH) {
        int k = i >> 6, n = i & 63;
        float v = W1[i];
        short h = f2bf_s(v);
        w1h[n * IN_F + k] = h;
        w1l[n * IN_F + k] = f2bf_s(v - bf2f_s(h));
    } else if (i < IN_F * NH + NH * NC) {
        int j = i - IN_F * NH;
        int k = j >> 4, c = j & 15;
        float v = W2[j];
        short h = f2bf_s(v);
        w2h[c * NH + k] = h;
        w2l[c * NH + k] = f2bf_s(v - bf2f_s(h));
    }
}

// ---------- encoder: z(bf16) = relu(X@W1+b1)@W2+b2 ; hid = temp[0]*z ----------
__global__ __launch_bounds__(256) void encoder_mfma(
    const float* __restrict__ X,
    const short* __restrict__ w1h, const short* __restrict__ w1l,
    const short* __restrict__ w2h, const short* __restrict__ w2l,
    const float* __restrict__ b1, const float* __restrict__ b2,
    const float* __restrict__ temp,
    u16* __restrict__ z, float* __restrict__ hid)
{
    __shared__ float hs[128 * 68];
    const int t = threadIdx.x;
    const int wave = t >> 6, lane = t & 63;
    const int lm = lane & 15, kg = lane >> 4;
    const int wrow = blockIdx.x * 128 + wave * 32;

    int r0 = wrow + lm;       if (r0 > NN - 1) r0 = NN - 1;
    int r1 = wrow + 16 + lm;  if (r1 > NN - 1) r1 = NN - 1;
    const float* xp0 = X + (size_t)r0 * IN_F + kg * 8;
    const float* xp1 = X + (size_t)r1 * IN_F + kg * 8;
    const short* bhp = w1h + lm * IN_F + kg * 8;
    const short* blp = w1l + lm * IN_F + kg * 8;

    f32x4 acc[2][4];
#pragma unroll
    for (int m = 0; m < 2; ++m)
#pragma unroll
        for (int n = 0; n < 4; ++n) acc[m][n] = (f32x4){0.f, 0.f, 0.f, 0.f};

    for (int kb = 0; kb < IN_F; kb += 32) {
        bf16x8 ah0, al0, ah1, al1;
        {
            const f32x4* p0 = reinterpret_cast<const f32x4*>(xp0 + kb);
            split8(p0[0], p0[1], ah0, al0);
            const f32x4* p1 = reinterpret_cast<const f32x4*>(xp1 + kb);
            split8(p1[0], p1[1], ah1, al1);
        }
#pragma unroll
        for (int nt = 0; nt < 4; ++nt) {
            bf16x8 bh = *reinterpret_cast<const bf16x8*>(bhp + nt * 16 * IN_F + kb);
            bf16x8 bl = *reinterpret_cast<const bf16x8*>(blp + nt * 16 * IN_F + kb);
            acc[0][nt] = mfma3(ah0, al0, bh, bl, acc[0][nt]);
            acc[1][nt] = mfma3(ah1, al1, bh, bl, acc[1][nt]);
        }
    }

    float b1v[4];
#pragma unroll
    for (int nt = 0; nt < 4; ++nt) b1v[nt] = b1[nt * 16 + lm];
#pragma unroll
    for (int m = 0; m < 2; ++m)
#pragma unroll
        for (int nt = 0; nt < 4; ++nt)
#pragma unroll
            for (int r = 0; r < 4; ++r) {
                float v = acc[m][nt][r] + b1v[nt];
                v = v > 0.f ? v : 0.f;
                hs[(wave * 32 + m * 16 + kg * 4 + r) * 68 + nt * 16 + lm] = v;
            }

    f32x4 acc2[2];
    acc2[0] = (f32x4){0.f, 0.f, 0.f, 0.f};
    acc2[1] = (f32x4){0.f, 0.f, 0.f, 0.f};
#pragma unroll
    for (int kb = 0; kb < NH; kb += 32) {
        bf16x8 bh = *reinterpret_cast<const bf16x8*>(w2h + lm * NH + kb + kg * 8);
        bf16x8 bl = *reinterpret_cast<const bf16x8*>(w2l + lm * NH + kb + kg * 8);
#pragma unroll
        for (int m = 0; m < 2; ++m) {
            const f32x4* hp = reinterpret_cast<const f32x4*>(
                &hs[(wave * 32 + m * 16 + lm) * 68 + kb + kg * 8]);
            bf16x8 ah, al;
            split8(hp[0], hp[1], ah, al);
            acc2[m] = mfma3(ah, al, bh, bl, acc2[m]);
        }
    }

    const float b2v = b2[lm];
    const float t0 = temp[0];
#pragma unroll
    for (int m = 0; m < 2; ++m)
#pragma unroll
        for (int r = 0; r < 4; ++r) {
            int node = wrow + m * 16 + kg * 4 + r;
            if (node < NN) {
                float zv = acc2[m][r] + b2v;
                z[(size_t)node * NC + lm] = (u16)f2bf_s(zv);
                hid[(size_t)node * NC + lm] = t0 * zv;
            }
        }
}

// ---------- init gcursor to fixed region bases ----------
__global__ __launch_bounds__(256) void init_cursor_kernel(int* __restrict__ gcur)
{
    int b = blockIdx.x * 256 + threadIdx.x;
    if (b < NBUCKP) gcur[b] = b * CAP;
}

// ---------- partition: edges -> fixed-cap bucket regions ----------
// pack (src | dlo<<24, w) as int2; dlo = dst & 255
__global__ __launch_bounds__(1024) void partition_kernel(
    const int* __restrict__ src, const int* __restrict__ dst,
    const float* __restrict__ w, int* __restrict__ gcur,
    int2* __restrict__ ew)
{
    __shared__ int h[16][NBUCKP];     // wave-privatized histograms (32 KB)
    __shared__ int base[NBUCKP];
    __shared__ int rnk[NBUCKP];
    const int t = threadIdx.x;
    const int wid = t >> 6;
    for (int i = t; i < 16 * NBUCKP; i += 1024) ((int*)h)[i] = 0;
    __syncthreads();
    const int s = blockIdx.x * PCHUNK;
    int e = s + PCHUNK; if (e > NE) e = NE;
    for (int i = s + t; i < e; i += 1024)
        atomicAdd(&h[wid][dst[i] >> 8], 1);
    __syncthreads();
    for (int b = t; b < NBUCKP; b += 1024) {
        int tot = 0;
#pragma unroll
        for (int ww = 0; ww < 16; ++ww) tot += h[ww][b];
        base[b] = tot ? atomicAdd(&gcur[b], tot) : 0;
        rnk[b] = 0;
    }
    __syncthreads();
    for (int i = s + t; i < e; i += 1024) {
        int d = dst[i];
        int b = d >> 8;
        int r = atomicAdd(&rnk[b], 1);
        unsigned x = (unsigned)src[i] | ((unsigned)(d & 255) << 24);
        ew[base[b] + r] = make_int2((int)x, __float_as_int(w[i]));
    }
}

// ---------- bucketfill: per coarse bucket, node-sort edges, emit rowse ----------
__global__ __launch_bounds__(256) void bucketfill_kernel(
    const int* __restrict__ gcur, long long* __restrict__ ew,
    int2* __restrict__ rowse)
{
    __shared__ long long buf[CAP];                 // 73728 B
    __shared__ int cnt[BSPAN], excl[BSPAN], rnk[BSPAN];
    const int b = blockIdx.x;
    const int base = b * CAP;
    int n = gcur[b] - base;
    if (n > CAP) n = CAP;
    const int t = threadIdx.x;
    cnt[t] = 0;
    __syncthreads();
    for (int i = t; i < n; i += 256) {
        long long v = ew[base + i];
        buf[i] = v;
        atomicAdd(&cnt[(int)((v >> 24) & 255)], 1);
    }
    __syncthreads();
    // exclusive scan of cnt[256] (Hillis-Steele in-place w/ barriers)
    int sv = cnt[t];
    int acc = sv;
    excl[t] = acc;
    __syncthreads();
    for (int off = 1; off < 256; off <<= 1) {
        int u = (t >= off) ? excl[t - off] : 0;
        __syncthreads();
        excl[t] += u;
        __syncthreads();
    }
    int myExcl = excl[t] - sv;
    __syncthreads();
    excl[t] = myExcl;
    rnk[t] = 0;
    int node = b * BSPAN + t;
    if (node < NN) rowse[node] = make_int2(base + myExcl, sv);
    __syncthreads();
    for (int i = t; i < n; i += 256) {
        long long v = buf[i];
        int d = (int)((v >> 24) & 255);
        int r = atomicAdd(&rnk[d], 1);
        ew[base + excl[d] + r] = v & 0xFFFFFFFF00FFFFFFll;
    }
}

// ---------- hop: r[d] = sum w*in[src] (bf16 in); out=bf16(r); hid += tk*r ----------
__global__ __launch_bounds__(256) void hop_kernel(
    const int2* __restrict__ rowse, const long long* __restrict__ ew,
    const u16* __restrict__ in, u16* __restrict__ out,
    float* __restrict__ hid, const float* __restrict__ temp, int k, int last)
{
    int tid = blockIdx.x * 256 + threadIdx.x;
    int d = tid >> 2, cg = tid & 3;
    if (d >= NN) return;
    int2 rs = rowse[d];
    int e = rs.x;
    const int e1 = rs.x + rs.y;
    const u16x4* inv = reinterpret_cast<const u16x4*>(in);
    f32x4 a0 = (f32x4){0.f, 0.f, 0.f, 0.f};
    f32x4 a1 = a0, a2 = a0, a3 = a0;
    for (; e + 3 < e1; e += 4) {
        long long q0 = __builtin_nontemporal_load(ew + e);
        long long q1 = __builtin_nontemporal_load(ew + e + 1);
        long long q2 = __builtin_nontemporal_load(ew + e + 2);
        long long q3 = __builtin_nontemporal_load(ew + e + 3);
        int s0 = (int)(q0 & 0x00FFFFFFll);
        int s1 = (int)(q1 & 0x00FFFFFFll);
        int s2 = (int)(q2 & 0x00FFFFFFll);
        int s3 = (int)(q3 & 0x00FFFFFFll);
        float w0 = __uint_as_float((unsigned)((unsigned long long)q0 >> 32));
        float w1 = __uint_as_float((unsigned)((unsigned long long)q1 >> 32));
        float w2 = __uint_as_float((unsigned)((unsigned long long)q2 >> 32));
        float w3 = __uint_as_float((unsigned)((unsigned long long)q3 >> 32));
        u16x4 v0 = inv[(size_t)s0 * 4 + cg];
        u16x4 v1 = inv[(size_t)s1 * 4 + cg];
        u16x4 v2 = inv[(size_t)s2 * 4 + cg];
        u16x4 v3 = inv[(size_t)s3 * 4 + cg];
        a0 += w0 * bf4_to_f32(v0);
        a1 += w1 * bf4_to_f32(v1);
        a2 += w2 * bf4_to_f32(v2);
        a3 += w3 * bf4_to_f32(v3);
    }
    for (; e < e1; ++e) {
        long long q0 = __builtin_nontemporal_load(ew + e);
        int s0 = (int)(q0 & 0x00FFFFFFll);
        float w0 = __uint_as_float((unsigned)((unsigned long long)q0 >> 32));
        a0 += w0 * bf4_to_f32(inv[(size_t)s0 * 4 + cg]);
    }
    f32x4 r = (a0 + a1) + (a2 + a3);
    size_t o = (size_t)d * 4 + cg;
    if (!last) {
        u16x4 ro;
        ro[0] = (u16)f2bf_s(r[0]);
        ro[1] = (u16)f2bf_s(r[1]);
        ro[2] = (u16)f2bf_s(r[2]);
        ro[3] = (u16)f2bf_s(r[3]);
        reinterpret_cast<u16x4*>(out)[o] = ro;
    }
    const float tk = temp[k];
    reinterpret_cast<f32x4*>(hid)[o] += tk * r;
}

// ---------- fallback (small ws): atomic scatter on bf16 state ----------
__global__ __launch_bounds__(256) void spmm_atomic_bf16(
    const int* __restrict__ src, const int* __restrict__ dst,
    const float* __restrict__ w, const u16* __restrict__ in,
    float* __restrict__ outf)
{
    int tid = blockIdx.x * 256 + threadIdx.x;
    int e = tid >> 4, c = tid & 15;
    if (e >= NE) return;
    float v = __uint_as_float((unsigned)in[(size_t)src[e] * NC + c] << 16);
    atomicAdd(&outf[(size_t)dst[e] * NC + c], w[e] * v);
}
__global__ __launch_bounds__(256) void axpy_quant_kernel(
    float* __restrict__ hid, const float* __restrict__ outf,
    u16* __restrict__ nextb, const float* __restrict__ temp, int k)
{
    int i = blockIdx.x * 256 + threadIdx.x;
    if (i < NN * NC) {
        float r = outf[i];
        hid[i] += temp[k] * r;
        nextb[i] = (u16)f2bf_s(r);
    }
}

extern "C" void kernel_launch(void* const* d_in, const int* in_sizes, int n_in,
                              void* d_out, int out_size, void* d_ws, size_t ws_size,
                              hipStream_t stream)
{
    const float* feature = (const float*)d_in[0];
    const float* W1      = (const float*)d_in[1];
    const float* b1      = (const float*)d_in[2];
    const float* W2      = (const float*)d_in[3];
    const float* b2      = (const float*)d_in[4];
    const int*   edges   = (const int*)d_in[5];
    const float* norm_A  = (const float*)d_in[6];
    const float* temp    = (const float*)d_in[7];
    const int* src = edges;
    const int* dst = edges + NE;
    float* hid = (float*)d_out;

    char* p = (char*)d_ws;
    size_t off = 0;
    auto carve = [&](size_t bytes) {
        void* r = p + off;
        off += (bytes + 255) & ~(size_t)255;
        return r;
    };
    u16*   zkA   = (u16*)carve((size_t)NN * NC * 2);
    u16*   zkB   = (u16*)carve((size_t)NN * NC * 2);
    short* w1h   = (short*)carve((size_t)IN_F * NH * 2);
    short* w1l   = (short*)carve((size_t)IN_F * NH * 2);
    short* w2h   = (short*)carve((size_t)NH * NC * 2);
    short* w2l   = (short*)carve((size_t)NH * NC * 2);
    int*   gcur  = (int*)carve((size_t)NBUCKP * 4);
    int2*  rowse = (int2*)carve((size_t)NN * 8);
    int2*  ew    = (int2*)carve((size_t)NBUCKC * CAP * 8);   // 28.8 MB
    const bool useCSR = (off <= ws_size);

    conv_w_kernel<<<(IN_F * NH + NH * NC + 255) / 256, 256, 0, stream>>>(
        W1, W2, w1h, w1l, w2h, w2l);
    encoder_mfma<<<(NN + 127) / 128, 256, 0, stream>>>(
        feature, w1h, w1l, w2h, w2l, b1, b2, temp, zkA, hid);

    if (useCSR) {
        init_cursor_kernel<<<(NBUCKP + 255) / 256, 256, 0, stream>>>(gcur);
        partition_kernel<<<PART_BLOCKS, 1024, 0, stream>>>(src, dst, norm_A,
                                                           gcur, ew);
        bucketfill_kernel<<<NBUCKC, 256, 0, stream>>>(gcur, (long long*)ew,
                                                      rowse);

        const int hopGrid = (NN * 4 + 255) / 256;    // 1563
        u16* cur = zkA;
        u16* nxt = zkB;
        for (int k = 1; k <= K_HOPS; ++k) {
            hop_kernel<<<hopGrid, 256, 0, stream>>>(
                rowse, (const long long*)ew, cur, nxt, hid, temp, k,
                k == K_HOPS);
            u16* t2 = cur; cur = nxt; nxt = t2;
        }
    } else {
        char* q = (char*)d_ws;
        size_t stride = ((size_t)NN * NC * 2 + 255) & ~(size_t)255;
        u16* inA = (u16*)q;
        u16* inB = (u16*)(q + stride);
        float* outf = (float*)(q + 2 * stride + 512 * 1024);
        const int spmmGrid = (NE * NC + 255) / 256;
        const int vecGrid  = (NN * NC + 255) / 256;
        u16* cur = inA; u16* nxt = inB;
        for (int k = 1; k <= K_HOPS; ++k) {
            hipMemsetAsync(outf, 0, (size_t)NN * NC * 4, stream);
            spmm_atomic_bf16<<<spmmGrid, 256, 0, stream>>>(src, dst, norm_A,
                                                           cur, outf);
            axpy_quant_kernel<<<vecGrid, 256, 0, stream>>>(hid, outf, nxt,
                                                           temp, k);
            u16* t2 = cur; cur = nxt; nxt = t2;
        }
    }
}